// Round 8
// baseline (313.739 us; speedup 1.0000x reference)
//
#include <hip/hip_runtime.h>
#include <hip/hip_bf16.h>

// WeisfeilerLehman: labels0 = argmax(x, -1); 3x ordered polynomial hash over edges.
// All arithmetic mod 2^32 (uint32 wrap) == reference int64 truncated to int32.
// R8: msd_scatter now sorts its chunk in LDS (pass A counts -> LDS scan ->
//     barrier-free LDS scatter) and streams each bucket segment to global in
//     one contiguous burst -> every buf line written once (kills the 6x write
//     amplification from partial-line dribbling across the >L2 working set).

#define WL_D 128
#define NCHUNK 256          // chunks == blocks for MSD pass (1 per CU)
#define MSDW 8              // waves per MSD scatter block (512 threads)
#define CMAX 12800          // max edges per chunk held in LDS (E <= 3,276,800)
#define BROWS 128           // rows per bucket; bucket = row >> 7, rl = row & 127
#define BBITS 7
#define NBMAX 1024          // max buckets supported (N <= 131072)

constexpr unsigned cpow(unsigned b, unsigned e) {
    unsigned p = 1;
    while (e) { if (e & 1u) p *= b; b *= b; e >>= 1u; }
    return p;
}
constexpr unsigned cinv31() {           // Newton: inverse of 31 mod 2^32
    unsigned x = 1;
    for (int i = 0; i < 6; ++i) x *= 2u - 31u * x;
    return x;
}
constexpr unsigned INV31_64 = cpow(cinv31(), 64);   // 31^-64 mod 2^32

__device__ inline unsigned dpow31(unsigned e) {
    unsigned p = 1, b = 31u;
    while (e) { if (e & 1u) p *= b; b *= b; e >>= 1u; }
    return p;
}

// mask of lanes whose low BITS bits of v match mine (inactive lanes use a
// sentinel outside the valid key range so they never match active lanes)
template <int BITS>
__device__ inline unsigned long long match_key(unsigned v) {
    unsigned long long m = ~0ull;
    #pragma unroll
    for (int b = 0; b < BITS; ++b) {
        unsigned long long s = __ballot((v >> b) & 1u);
        m &= ((v >> b) & 1u) ? s : ~s;
    }
    return m;
}

__global__ void wl_argmax(const float* __restrict__ x, unsigned* __restrict__ lab0, int n) {
    int wave = (int)((blockIdx.x * blockDim.x + threadIdx.x) >> 6);
    int lane = threadIdx.x & 63;
    if (wave >= n) return;
    const float* xr = x + (size_t)wave * WL_D;
    float v0 = xr[lane];
    float v1 = xr[lane + 64];
    float bv; int bi;
    if (v1 > v0) { bv = v1; bi = lane + 64; } else { bv = v0; bi = lane; }
    #pragma unroll
    for (int off = 32; off > 0; off >>= 1) {
        float ov = __shfl_down(bv, off, 64);
        int   oi = __shfl_down(bi, off, 64);
        if (ov > bv || (ov == bv && oi < bi)) { bv = ov; bi = oi; }
    }
    if (lane == 0) lab0[wave] = (unsigned)bi;
}

// ---- two-level exclusive scan (1024-wide level 1; level 2 folded at use sites) ----
__global__ void wl_scan1(const unsigned* __restrict__ in, unsigned* __restrict__ out,
                         unsigned* __restrict__ bsums, int n) {
    __shared__ unsigned tmp[1024];
    int i = blockIdx.x * 1024 + threadIdx.x;
    unsigned v = (i < n) ? in[i] : 0u;
    tmp[threadIdx.x] = v;
    __syncthreads();
    for (int off = 1; off < 1024; off <<= 1) {
        unsigned t = (threadIdx.x >= (unsigned)off) ? tmp[threadIdx.x - off] : 0u;
        __syncthreads();
        tmp[threadIdx.x] += t;
        __syncthreads();
    }
    if (i < n) out[i] = tmp[threadIdx.x] - v;   // exclusive within block
    if (threadIdx.x == 1023) bsums[blockIdx.x] = tmp[1023];
}

__global__ void wl_scan2(unsigned* __restrict__ bsums, int nb) {
    __shared__ unsigned tmp[1024];
    int t = threadIdx.x;
    unsigned v = (t < nb) ? bsums[t] : 0u;
    tmp[t] = v;
    __syncthreads();
    for (int off = 1; off < 1024; off <<= 1) {
        unsigned s = (t >= off) ? tmp[t - off] : 0u;
        __syncthreads();
        tmp[t] += s;
        __syncthreads();
    }
    if (t < nb) bsums[t] = tmp[t] - v;          // exclusive
}

// ---- MSD pass 1: per-chunk histogram over buckets, layout hist[bucket][chunk] ----
__global__ void wl_msd_hist(const int* __restrict__ ei, unsigned* __restrict__ hist,
                            int E, int chunk, int nbuckets) {
    __shared__ unsigned h[NBMAX];
    int c = blockIdx.x;
    for (int i = threadIdx.x; i < nbuckets; i += 256) h[i] = 0;
    __syncthreads();
    int base = c * chunk;
    int lim = min(base + chunk, E);
    for (int e = base + threadIdx.x; e < lim; e += 256)
        atomicAdd(&h[((unsigned)ei[e]) >> BBITS], 1u);   // LDS atomic
    __syncthreads();
    for (int b = threadIdx.x; b < nbuckets; b += 256)
        hist[(size_t)b * NCHUNK + c] = h[b];
}

// ---- MSD pass 2: local counting sort of the chunk in LDS, then streamed
//      per-bucket burst copy to global (each buf line written exactly once) ----
__global__ void __launch_bounds__(512)
wl_msd_scatter(const int* __restrict__ ei, const unsigned* __restrict__ choff,
               const unsigned* __restrict__ bs, unsigned* __restrict__ buf,
               int E, int chunk, int nbuckets) {
    __shared__ unsigned short wcnt[MSDW][NBMAX];   // counts -> local cursors
    __shared__ unsigned loff[NBMAX];               // local exclusive bucket offsets
    __shared__ unsigned segtot[16];
    __shared__ unsigned data[CMAX];                // chunk sorted by bucket (packed)
    int c = blockIdx.x, t = threadIdx.x;
    int lane = t & 63, w = t >> 6;
    for (int i = t; i < MSDW * NBMAX; i += 512) ((unsigned short*)wcnt)[i] = 0;
    __syncthreads();
    int base = c * chunk;
    int lim  = min(base + chunk, E);
    int blocklen = lim - base;
    int sub  = (chunk + MSDW - 1) / MSDW;
    int wbeg = base + w * sub;
    int wend = min(wbeg + sub, lim);
    int nbat = (wbeg < wend) ? ((wend - wbeg + 63) >> 6) : 0;
    unsigned long long lmask = (1ull << lane) - 1ull;
    // pass A: per-wave bucket counts (leader-lane RMW, lockstep-safe)
    for (int bt = 0; bt < nbat; ++bt) {
        int e = wbeg + bt * 64 + lane;
        bool act = (e < wend);
        unsigned v = act ? (((unsigned)ei[e]) >> BBITS) : (NBMAX - 1u);
        unsigned long long m = match_key<10>(v);
        unsigned before = (unsigned)__popcll(m & lmask);
        unsigned total  = (unsigned)__popcll(m);
        if (act && before == 0u)
            wcnt[w][v] = (unsigned short)(wcnt[w][v] + total);
    }
    __syncthreads();
    // totals per bucket
    for (int v = t; v < NBMAX; v += 512) {
        unsigned s = 0;
        #pragma unroll
        for (int w2 = 0; w2 < MSDW; ++w2) s += wcnt[w2][v];
        loff[v] = s;
    }
    __syncthreads();
    // hierarchical exclusive scan of loff (16 segments of 64, shfl-based)
    for (int s = w; s < 16; s += MSDW) {
        unsigned orig = loff[s * 64 + lane];
        unsigned incl = orig;
        #pragma unroll
        for (int o = 1; o < 64; o <<= 1) {
            unsigned u = __shfl_up(incl, o, 64);
            if (lane >= o) incl += u;
        }
        loff[s * 64 + lane] = incl - orig;     // exclusive within segment
        if (lane == 63) segtot[s] = incl;
    }
    __syncthreads();
    if (w == 0) {
        unsigned sv = (lane < 16) ? segtot[lane] : 0u;
        unsigned incl = sv;
        #pragma unroll
        for (int o = 1; o < 16; o <<= 1) {
            unsigned u = __shfl_up(incl, o, 64);
            if (lane >= o) incl += u;
        }
        if (lane < 16) segtot[lane] = incl - sv;   // exclusive over segments
    }
    __syncthreads();
    for (int v = t; v < NBMAX; v += 512) loff[v] += segtot[v >> 6];
    __syncthreads();
    // seed per-wave local cursors in wave order (reuse wcnt as cursors)
    for (int v = t; v < NBMAX; v += 512) {
        unsigned run = loff[v];
        #pragma unroll
        for (int w2 = 0; w2 < MSDW; ++w2) {
            unsigned cnt = wcnt[w2][v];
            wcnt[w2][v] = (unsigned short)run;
            run += cnt;
        }
    }
    __syncthreads();
    // pass B: stable local scatter into LDS, barrier-free per-wave cursors
    for (int bt = 0; bt < nbat; ++bt) {
        int e = wbeg + bt * 64 + lane;
        bool act = (e < wend);
        unsigned r   = act ? (unsigned)ei[e] : 0u;
        unsigned col = act ? (unsigned)ei[(size_t)E + e] : 0u;
        unsigned v = act ? (r >> BBITS) : (NBMAX - 1u);
        unsigned long long m = match_key<10>(v);
        unsigned before = (unsigned)__popcll(m & lmask);
        unsigned total  = (unsigned)__popcll(m);
        int leader = __ffsll(m) - 1;
        unsigned base0 = 0;
        if (act && before == 0u) {
            base0 = wcnt[w][v];
            wcnt[w][v] = (unsigned short)(base0 + total);
        }
        base0 = __shfl(base0, leader, 64);
        if (act) data[base0 + before] = ((r & (BROWS - 1u)) << 24) | col;
    }
    __syncthreads();
    // write-out: each bucket's local segment -> one contiguous global burst
    for (int v = w; v < nbuckets; v += MSDW) {
        unsigned ls = loff[v];
        unsigned le = (v + 1 < NBMAX) ? loff[v + 1] : (unsigned)blocklen;
        unsigned len = le - ls;
        if (len == 0) continue;
        size_t idx = (size_t)v * NCHUNK + c;
        unsigned gs = choff[idx] + bs[idx >> 10];
        for (unsigned j = lane; j < len; j += 64u)
            buf[gs + j] = data[ls + j];
    }
}

// ---- per-bucket stable counting sort by rl; emits rs, deg, ordered col-CSR ----
__global__ void wl_bucket_sort(const unsigned* __restrict__ buf, const unsigned* __restrict__ choff,
                               const unsigned* __restrict__ bs, unsigned* __restrict__ csr,
                               unsigned* __restrict__ rs_g, unsigned* __restrict__ deg_g,
                               int N, int E, int nbuckets) {
    __shared__ unsigned h2[4][BROWS];
    __shared__ unsigned off[BROWS];
    int b = blockIdx.x, t = threadIdx.x;
    int lane = t & 63, w = t >> 6;
    size_t i0 = (size_t)b * NCHUNK;
    unsigned start = choff[i0] + bs[i0 >> 10];
    unsigned end;
    if (b + 1 < nbuckets) { size_t i1 = (size_t)(b + 1) * NCHUNK; end = choff[i1] + bs[i1 >> 10]; }
    else end = (unsigned)E;
    unsigned len = end - start;
    for (int i = t; i < 4 * BROWS; i += 256) ((unsigned*)h2)[i] = 0u;
    __syncthreads();
    unsigned sub  = (len + 3u) / 4u;
    unsigned wbeg = w * sub;
    unsigned wend = min(wbeg + sub, len);
    int nbat = (wbeg < wend) ? (int)((wend - wbeg + 63u) >> 6) : 0;
    unsigned long long lmask = (1ull << lane) - 1ull;
    // pass A: per-wave rl counts
    for (int bt = 0; bt < nbat; ++bt) {
        unsigned i = wbeg + (unsigned)(bt * 64 + lane);
        bool act = (i < wend);
        unsigned v = act ? (buf[start + i] >> 24) : 255u;
        unsigned long long m = match_key<8>(v);
        unsigned before = (unsigned)__popcll(m & lmask);
        unsigned total  = (unsigned)__popcll(m);
        if (act && before == 0u) h2[w][v] += total;
    }
    __syncthreads();
    // deg + exclusive scan over rl
    unsigned hv = 0;
    if (t < BROWS) {
        hv = h2[0][t] + h2[1][t] + h2[2][t] + h2[3][t];
        off[t] = hv;
    }
    __syncthreads();
    for (int o = 1; o < BROWS; o <<= 1) {
        unsigned s = (t < BROWS && t >= o) ? off[t - o] : 0u;
        __syncthreads();
        if (t < BROWS) off[t] += s;
        __syncthreads();
    }
    if (t < BROWS) {
        unsigned excl = off[t] - hv;
        int row = b * BROWS + t;
        if (row < N) { rs_g[row] = start + excl; deg_g[row] = hv; }
        unsigned g = start + excl;
        #pragma unroll
        for (int w2 = 0; w2 < 4; ++w2) {
            unsigned cnt = h2[w2][t];
            h2[w2][t] = g;
            g += cnt;
        }
    }
    __syncthreads();
    // pass B: rank + scatter into final CSR slice, barrier-free
    for (int bt = 0; bt < nbat; ++bt) {
        unsigned i = wbeg + (unsigned)(bt * 64 + lane);
        bool act = (i < wend);
        unsigned p = act ? buf[start + i] : 0u;
        unsigned v = act ? (p >> 24) : 255u;
        unsigned long long m = match_key<8>(v);
        unsigned before = (unsigned)__popcll(m & lmask);
        unsigned total  = (unsigned)__popcll(m);
        int leader = __ffsll(m) - 1;
        unsigned base0 = 0;
        if (act && before == 0u) { base0 = h2[w][v]; h2[w][v] = base0 + total; }
        base0 = __shfl(base0, leader, 64);
        if (act) csr[base0 + before] = p & 0xFFFFFFu;
    }
}

// One wave per row: new[r] = sum_j lab[col_j] * 31^(d-1-j)  (mod 2^32).
__global__ void wl_prop(const unsigned* __restrict__ col_csr, const unsigned* __restrict__ rs,
                        const unsigned* __restrict__ deg, const unsigned* __restrict__ lin,
                        unsigned* __restrict__ lout, int n) {
    int r = (int)((blockIdx.x * blockDim.x + threadIdx.x) >> 6);
    int lane = threadIdx.x & 63;
    if (r >= n) return;
    unsigned start = rs[r], d = deg[r];
    unsigned acc = 0;
    if ((unsigned)lane < d) {
        unsigned p = dpow31(d - 1u - (unsigned)lane);
        for (unsigned j = (unsigned)lane; j < d; j += 64u) {
            acc += lin[col_csr[start + j]] * p;
            p *= INV31_64;
        }
    }
    #pragma unroll
    for (int off = 32; off > 0; off >>= 1) acc += __shfl_xor(acc, off, 64);
    if (lane == 0) lout[r] = acc;
}

__global__ void wl_write_out(const unsigned* __restrict__ l0, const unsigned* __restrict__ l1,
                             const unsigned* __restrict__ l2, const unsigned* __restrict__ l3,
                             int* __restrict__ out, int n) {
    int i = blockIdx.x * blockDim.x + threadIdx.x;
    if (i >= n) return;
    int a0 = (int)l0[i], a1 = (int)l1[i], a2 = (int)l2[i], a3 = (int)l3[i];
    out[i]         = a3;   // labels3 (final)
    out[n + i]     = a0;   // labels0
    out[2 * n + i] = a1;   // labels1
    out[3 * n + i] = a2;   // labels2
    out[4 * n + i] = a3;   // labels3
}

extern "C" void kernel_launch(void* const* d_in, const int* in_sizes, int n_in,
                              void* d_out, int out_size, void* d_ws, size_t ws_size,
                              hipStream_t stream) {
    const float* x  = (const float*)d_in[0];
    const int*   ei = (const int*)d_in[1];
    int* out = (int*)d_out;

    const int N = in_sizes[0] / WL_D;
    const int E = in_sizes[1] / 2;
    const int chunk    = (E + NCHUNK - 1) / NCHUNK;    // 12500 for E=3.2M (<= CMAX)
    const int nbuckets = (N + BROWS - 1) / BROWS;      // 782 for N=100k
    const int L  = nbuckets * NCHUNK;                  // 200,192 scan length
    const int nb = (L + 1023) / 1024;                  // 196 <= 1024

    // workspace layout (uint32 units) — everything written before read, no memset
    unsigned* ws   = (unsigned*)d_ws;
    unsigned* lab0 = ws;               // N
    unsigned* lab1 = lab0 + N;         // N
    unsigned* lab2 = lab1 + N;         // N
    unsigned* lab3 = lab2 + N;         // N
    unsigned* rs   = lab3 + N;         // N
    unsigned* deg  = rs + N;           // N
    unsigned* bs   = deg + N;          // 1024
    unsigned* hist = bs + 1024;        // L   (block-scanned in place; +bs at use sites)
    unsigned* buf  = hist + L;         // E   (bucket-ordered packed (rl<<24)|col)
    unsigned* csr  = buf + E;          // E   (final: cols in edge order per row)

    const int BT = 256;
    int gridN = (N + BT - 1) / BT;
    int gridW = (N + 3) / 4;                   // wave-per-row kernels

    wl_argmax<<<gridW, BT, 0, stream>>>(x, lab0, N);

    wl_msd_hist<<<NCHUNK, BT, 0, stream>>>(ei, hist, E, chunk, nbuckets);
    wl_scan1<<<nb, 1024, 0, stream>>>(hist, hist, bs, L);
    wl_scan2<<<1, 1024, 0, stream>>>(bs, nb);
    wl_msd_scatter<<<NCHUNK, 512, 0, stream>>>(ei, hist, bs, buf, E, chunk, nbuckets);
    wl_bucket_sort<<<nbuckets, BT, 0, stream>>>(buf, hist, bs, csr, rs, deg, N, E, nbuckets);

    wl_prop<<<gridW, BT, 0, stream>>>(csr, rs, deg, lab0, lab1, N);
    wl_prop<<<gridW, BT, 0, stream>>>(csr, rs, deg, lab1, lab2, N);
    wl_prop<<<gridW, BT, 0, stream>>>(csr, rs, deg, lab2, lab3, N);

    wl_write_out<<<gridN, BT, 0, stream>>>(lab0, lab1, lab2, lab3, out, N);
}

// Round 9
// 306.315 us; speedup vs baseline: 1.0242x; 1.0242x over previous
//
#include <hip/hip_runtime.h>
#include <hip/hip_bf16.h>

// WeisfeilerLehman: labels0 = argmax(x, -1); 3x ordered polynomial hash over edges.
// All arithmetic mod 2^32 (uint32 wrap) == reference int64 truncated to int32.
// R9: coarser MSD radix (256-row buckets, 391 total) + R7-style direct global
//     scatter. Fewer open partial lines (391x64B=25KB/block) -> dirty lines
//     survive in L2 and coalesce, killing write amplification WITHOUT the R8
//     LDS-staging compute overhead. bucket_sort: BROWS=256, 391 blocks.

#define WL_D 128
#define NCHUNK 256          // chunks == blocks for MSD pass (1 per CU)
#define MSDW 8              // waves per MSD scatter block (512 threads)
#define BROWS 256           // rows per bucket; bucket = row >> 8, rl = row & 255
#define BBITS 8
#define NBMAX 512           // max buckets (N <= 131072)

constexpr unsigned cpow(unsigned b, unsigned e) {
    unsigned p = 1;
    while (e) { if (e & 1u) p *= b; b *= b; e >>= 1u; }
    return p;
}
constexpr unsigned cinv31() {           // Newton: inverse of 31 mod 2^32
    unsigned x = 1;
    for (int i = 0; i < 6; ++i) x *= 2u - 31u * x;
    return x;
}
constexpr unsigned INV31_64 = cpow(cinv31(), 64);   // 31^-64 mod 2^32

__device__ inline unsigned dpow31(unsigned e) {
    unsigned p = 1, b = 31u;
    while (e) { if (e & 1u) p *= b; b *= b; e >>= 1u; }
    return p;
}

// mask of lanes whose low BITS bits of v match mine (inactive lanes use a
// sentinel outside the valid key range so they never match active lanes)
template <int BITS>
__device__ inline unsigned long long match_key(unsigned v) {
    unsigned long long m = ~0ull;
    #pragma unroll
    for (int b = 0; b < BITS; ++b) {
        unsigned long long s = __ballot((v >> b) & 1u);
        m &= ((v >> b) & 1u) ? s : ~s;
    }
    return m;
}

__global__ void wl_argmax(const float* __restrict__ x, unsigned* __restrict__ lab0, int n) {
    int wave = (int)((blockIdx.x * blockDim.x + threadIdx.x) >> 6);
    int lane = threadIdx.x & 63;
    if (wave >= n) return;
    const float* xr = x + (size_t)wave * WL_D;
    float v0 = xr[lane];
    float v1 = xr[lane + 64];
    float bv; int bi;
    if (v1 > v0) { bv = v1; bi = lane + 64; } else { bv = v0; bi = lane; }
    #pragma unroll
    for (int off = 32; off > 0; off >>= 1) {
        float ov = __shfl_down(bv, off, 64);
        int   oi = __shfl_down(bi, off, 64);
        if (ov > bv || (ov == bv && oi < bi)) { bv = ov; bi = oi; }
    }
    if (lane == 0) lab0[wave] = (unsigned)bi;
}

// ---- two-level exclusive scan (1024-wide level 1; level 2 folded at use sites) ----
__global__ void wl_scan1(const unsigned* __restrict__ in, unsigned* __restrict__ out,
                         unsigned* __restrict__ bsums, int n) {
    __shared__ unsigned tmp[1024];
    int i = blockIdx.x * 1024 + threadIdx.x;
    unsigned v = (i < n) ? in[i] : 0u;
    tmp[threadIdx.x] = v;
    __syncthreads();
    for (int off = 1; off < 1024; off <<= 1) {
        unsigned t = (threadIdx.x >= (unsigned)off) ? tmp[threadIdx.x - off] : 0u;
        __syncthreads();
        tmp[threadIdx.x] += t;
        __syncthreads();
    }
    if (i < n) out[i] = tmp[threadIdx.x] - v;   // exclusive within block
    if (threadIdx.x == 1023) bsums[blockIdx.x] = tmp[1023];
}

__global__ void wl_scan2(unsigned* __restrict__ bsums, int nb) {
    __shared__ unsigned tmp[1024];
    int t = threadIdx.x;
    unsigned v = (t < nb) ? bsums[t] : 0u;
    tmp[t] = v;
    __syncthreads();
    for (int off = 1; off < 1024; off <<= 1) {
        unsigned s = (t >= off) ? tmp[t - off] : 0u;
        __syncthreads();
        tmp[t] += s;
        __syncthreads();
    }
    if (t < nb) bsums[t] = tmp[t] - v;          // exclusive
}

// ---- MSD pass 1: per-chunk histogram over buckets, layout hist[bucket][chunk] ----
__global__ void wl_msd_hist(const int* __restrict__ ei, unsigned* __restrict__ hist,
                            int E, int chunk, int nbuckets) {
    __shared__ unsigned h[NBMAX];
    int c = blockIdx.x;
    for (int i = threadIdx.x; i < nbuckets; i += 256) h[i] = 0;
    __syncthreads();
    int base = c * chunk;
    int lim = min(base + chunk, E);
    for (int e = base + threadIdx.x; e < lim; e += 256)
        atomicAdd(&h[((unsigned)ei[e]) >> BBITS], 1u);   // LDS atomic
    __syncthreads();
    for (int b = threadIdx.x; b < nbuckets; b += 256)
        hist[(size_t)b * NCHUNK + c] = h[b];
}

// ---- MSD pass 2: stable direct scatter of packed (rl<<24)|col into bucket order.
// Per-wave contiguous sub-chunks; per-(wave,bucket) cursors in LDS; no atomics,
// 2 barriers total. 391 buckets -> ~25 KB of open partial lines per block,
// which survive in L2 between cursor visits (write-combined there).
__global__ void __launch_bounds__(512)
wl_msd_scatter(const int* __restrict__ ei, const unsigned* __restrict__ choff,
               const unsigned* __restrict__ bs, unsigned* __restrict__ buf,
               int E, int chunk, int nbuckets) {
    __shared__ unsigned wbase[MSDW][NBMAX];   // 16 KB
    int c = blockIdx.x, t = threadIdx.x;
    int lane = t & 63, w = t >> 6;
    for (int i = t; i < MSDW * NBMAX; i += 512) ((unsigned*)wbase)[i] = 0u;
    __syncthreads();
    int base = c * chunk;
    int lim  = min(base + chunk, E);
    int sub  = (chunk + MSDW - 1) / MSDW;
    int wbeg = base + w * sub;
    int wend = min(wbeg + sub, lim);
    int nbat = (wbeg < wend) ? ((wend - wbeg + 63) >> 6) : 0;
    unsigned long long lmask = (1ull << lane) - 1ull;
    // pass A: per-wave bucket counts (leader-lane RMW, lockstep-safe)
    for (int bt = 0; bt < nbat; ++bt) {
        int e = wbeg + bt * 64 + lane;
        bool act = (e < wend);
        unsigned v = act ? (((unsigned)ei[e]) >> BBITS) : (NBMAX - 1u);
        unsigned long long m = match_key<9>(v);
        unsigned before = (unsigned)__popcll(m & lmask);
        unsigned total  = (unsigned)__popcll(m);
        if (act && before == 0u) wbase[w][v] += total;
    }
    __syncthreads();
    // seed cursors: global base for (bucket, wave) in wave order
    for (int v = t; v < nbuckets; v += 512) {
        size_t idx = (size_t)v * NCHUNK + c;
        unsigned g = choff[idx] + bs[idx >> 10];
        #pragma unroll
        for (int w2 = 0; w2 < MSDW; ++w2) {
            unsigned cnt = wbase[w2][v];
            wbase[w2][v] = g;
            g += cnt;
        }
    }
    __syncthreads();
    // pass B: rank + scatter, barrier-free (each wave owns its cursor row)
    for (int bt = 0; bt < nbat; ++bt) {
        int e = wbeg + bt * 64 + lane;
        bool act = (e < wend);
        unsigned r   = act ? (unsigned)ei[e] : 0u;
        unsigned col = act ? (unsigned)ei[(size_t)E + e] : 0u;
        unsigned v = act ? (r >> BBITS) : (NBMAX - 1u);
        unsigned long long m = match_key<9>(v);
        unsigned before = (unsigned)__popcll(m & lmask);
        unsigned total  = (unsigned)__popcll(m);
        int leader = __ffsll(m) - 1;
        unsigned base0 = 0;
        if (act && before == 0u) { base0 = wbase[w][v]; wbase[w][v] = base0 + total; }
        base0 = __shfl(base0, leader, 64);
        if (act) buf[base0 + before] = ((r & (BROWS - 1u)) << 24) | col;
    }
}

// ---- per-bucket stable counting sort by rl; emits rs, deg, ordered col-CSR ----
// 391 blocks x 256 threads; per-wave cursors; 3 barriers + scan barriers.
__global__ void wl_bucket_sort(const unsigned* __restrict__ buf, const unsigned* __restrict__ choff,
                               const unsigned* __restrict__ bs, unsigned* __restrict__ csr,
                               unsigned* __restrict__ rs_g, unsigned* __restrict__ deg_g,
                               int N, int E, int nbuckets) {
    __shared__ unsigned h2[4][BROWS];
    __shared__ unsigned off[BROWS];
    int b = blockIdx.x, t = threadIdx.x;
    int lane = t & 63, w = t >> 6;
    size_t i0 = (size_t)b * NCHUNK;
    unsigned start = choff[i0] + bs[i0 >> 10];
    unsigned end;
    if (b + 1 < nbuckets) { size_t i1 = (size_t)(b + 1) * NCHUNK; end = choff[i1] + bs[i1 >> 10]; }
    else end = (unsigned)E;
    unsigned len = end - start;
    for (int i = t; i < 4 * BROWS; i += 256) ((unsigned*)h2)[i] = 0u;
    __syncthreads();
    unsigned sub  = (len + 3u) / 4u;
    unsigned wbeg = w * sub;
    unsigned wend = min(wbeg + sub, len);
    int nbat = (wbeg < wend) ? (int)((wend - wbeg + 63u) >> 6) : 0;
    unsigned long long lmask = (1ull << lane) - 1ull;
    // pass A: per-wave rl counts
    for (int bt = 0; bt < nbat; ++bt) {
        unsigned i = wbeg + (unsigned)(bt * 64 + lane);
        bool act = (i < wend);
        unsigned v = act ? (buf[start + i] >> 24) : 511u;   // sentinel >= BROWS
        unsigned long long m = match_key<9>(v);
        unsigned before = (unsigned)__popcll(m & lmask);
        unsigned total  = (unsigned)__popcll(m);
        if (act && before == 0u) h2[w][v] += total;
    }
    __syncthreads();
    // deg + exclusive scan over rl (256 entries, 256 threads)
    unsigned hv = h2[0][t] + h2[1][t] + h2[2][t] + h2[3][t];
    off[t] = hv;
    __syncthreads();
    for (int o = 1; o < BROWS; o <<= 1) {
        unsigned s = (t >= o) ? off[t - o] : 0u;
        __syncthreads();
        off[t] += s;
        __syncthreads();
    }
    {
        unsigned excl = off[t] - hv;
        int row = b * BROWS + t;
        if (row < N) { rs_g[row] = start + excl; deg_g[row] = hv; }
        unsigned g = start + excl;
        #pragma unroll
        for (int w2 = 0; w2 < 4; ++w2) {
            unsigned cnt = h2[w2][t];
            h2[w2][t] = g;
            g += cnt;
        }
    }
    __syncthreads();
    // pass B: rank + scatter into final CSR slice, barrier-free
    for (int bt = 0; bt < nbat; ++bt) {
        unsigned i = wbeg + (unsigned)(bt * 64 + lane);
        bool act = (i < wend);
        unsigned p = act ? buf[start + i] : 0u;
        unsigned v = act ? (p >> 24) : 511u;
        unsigned long long m = match_key<9>(v);
        unsigned before = (unsigned)__popcll(m & lmask);
        unsigned total  = (unsigned)__popcll(m);
        int leader = __ffsll(m) - 1;
        unsigned base0 = 0;
        if (act && before == 0u) { base0 = h2[w][v]; h2[w][v] = base0 + total; }
        base0 = __shfl(base0, leader, 64);
        if (act) csr[base0 + before] = p & 0xFFFFFFu;
    }
}

// One wave per row: new[r] = sum_j lab[col_j] * 31^(d-1-j)  (mod 2^32).
__global__ void wl_prop(const unsigned* __restrict__ col_csr, const unsigned* __restrict__ rs,
                        const unsigned* __restrict__ deg, const unsigned* __restrict__ lin,
                        unsigned* __restrict__ lout, int n) {
    int r = (int)((blockIdx.x * blockDim.x + threadIdx.x) >> 6);
    int lane = threadIdx.x & 63;
    if (r >= n) return;
    unsigned start = rs[r], d = deg[r];
    unsigned acc = 0;
    if ((unsigned)lane < d) {
        unsigned p = dpow31(d - 1u - (unsigned)lane);
        for (unsigned j = (unsigned)lane; j < d; j += 64u) {
            acc += lin[col_csr[start + j]] * p;
            p *= INV31_64;
        }
    }
    #pragma unroll
    for (int off = 32; off > 0; off >>= 1) acc += __shfl_xor(acc, off, 64);
    if (lane == 0) lout[r] = acc;
}

__global__ void wl_write_out(const unsigned* __restrict__ l0, const unsigned* __restrict__ l1,
                             const unsigned* __restrict__ l2, const unsigned* __restrict__ l3,
                             int* __restrict__ out, int n) {
    int i = blockIdx.x * blockDim.x + threadIdx.x;
    if (i >= n) return;
    int a0 = (int)l0[i], a1 = (int)l1[i], a2 = (int)l2[i], a3 = (int)l3[i];
    out[i]         = a3;   // labels3 (final)
    out[n + i]     = a0;   // labels0
    out[2 * n + i] = a1;   // labels1
    out[3 * n + i] = a2;   // labels2
    out[4 * n + i] = a3;   // labels3
}

extern "C" void kernel_launch(void* const* d_in, const int* in_sizes, int n_in,
                              void* d_out, int out_size, void* d_ws, size_t ws_size,
                              hipStream_t stream) {
    const float* x  = (const float*)d_in[0];
    const int*   ei = (const int*)d_in[1];
    int* out = (int*)d_out;

    const int N = in_sizes[0] / WL_D;
    const int E = in_sizes[1] / 2;
    const int chunk    = (E + NCHUNK - 1) / NCHUNK;    // 12500 for E=3.2M
    const int nbuckets = (N + BROWS - 1) / BROWS;      // 391 for N=100k
    const int L  = nbuckets * NCHUNK;                  // 100,096 scan length
    const int nb = (L + 1023) / 1024;                  // 98 <= 1024

    // workspace layout (uint32 units) — everything written before read, no memset
    unsigned* ws   = (unsigned*)d_ws;
    unsigned* lab0 = ws;               // N
    unsigned* lab1 = lab0 + N;         // N
    unsigned* lab2 = lab1 + N;         // N
    unsigned* lab3 = lab2 + N;         // N
    unsigned* rs   = lab3 + N;         // N
    unsigned* deg  = rs + N;           // N
    unsigned* bs   = deg + N;          // 1024
    unsigned* hist = bs + 1024;        // L   (block-scanned in place; +bs at use sites)
    unsigned* buf  = hist + L;         // E   (bucket-ordered packed (rl<<24)|col)
    unsigned* csr  = buf + E;          // E   (final: cols in edge order per row)

    const int BT = 256;
    int gridN = (N + BT - 1) / BT;
    int gridW = (N + 3) / 4;                   // wave-per-row kernels

    wl_argmax<<<gridW, BT, 0, stream>>>(x, lab0, N);

    wl_msd_hist<<<NCHUNK, BT, 0, stream>>>(ei, hist, E, chunk, nbuckets);
    wl_scan1<<<nb, 1024, 0, stream>>>(hist, hist, bs, L);
    wl_scan2<<<1, 1024, 0, stream>>>(bs, nb);
    wl_msd_scatter<<<NCHUNK, 512, 0, stream>>>(ei, hist, bs, buf, E, chunk, nbuckets);
    wl_bucket_sort<<<nbuckets, BT, 0, stream>>>(buf, hist, bs, csr, rs, deg, N, E, nbuckets);

    wl_prop<<<gridW, BT, 0, stream>>>(csr, rs, deg, lab0, lab1, N);
    wl_prop<<<gridW, BT, 0, stream>>>(csr, rs, deg, lab1, lab2, N);
    wl_prop<<<gridW, BT, 0, stream>>>(csr, rs, deg, lab2, lab3, N);

    wl_write_out<<<gridN, BT, 0, stream>>>(lab0, lab1, lab2, lab3, out, N);
}